// Round 1
// 140.858 us; speedup vs baseline: 1.0058x; 1.0058x over previous
//
#include <hip/hip_runtime.h>

typedef unsigned short u16;
typedef unsigned int u32;
typedef float f32x4 __attribute__((ext_vector_type(4)));
typedef __fp16 f16x2 __attribute__((ext_vector_type(2)));
typedef __fp16 half8 __attribute__((ext_vector_type(8)));
typedef unsigned int uint2v __attribute__((ext_vector_type(2)));
typedef unsigned int uint4v __attribute__((ext_vector_type(4)));

#define STRW 72           // u16 stride for weight tiles (144B rows, 16B-aligned)
#define STRU 36           // uint stride for per-wave scratch
#define LENT 998
#define NSAMP 63872       // 64 * 998
#define TILE_U16 4608     // 64*STRW
#define INVS 4.8828125e-4f  // 2^-11, exact

// ---- workspace layout (R17) -----------------------------------------------
#define IMG_BYTES 18432                         // hi(9216) + lo(9216) per (layer,l)
#define WS_VEC_OFF (16 * IMG_BYTES)             // 294912: [l][w0c|b1|b2|w3][64] f32
#define WS_E0_OFF  (WS_VEC_OFF + 8 * 256 * 4)   // 303104: [t][l][64] f32
#define WS_NEED    ((size_t)WS_E0_OFF + (size_t)LENT * 512 * 4)  // 2,347,008 B

#define LDSFENCE() asm volatile("s_waitcnt lgkmcnt(0)" ::: "memory")

// async global->LDS, 16B/lane; LDS dest is wave-uniform base + lane*16
static __device__ __forceinline__ void gll16(const void* g, void* l) {
    __builtin_amdgcn_global_load_lds(
        (const __attribute__((address_space(1))) void*)g,
        (__attribute__((address_space(3))) void*)l, 16, 0, 0);
}

// fp16 2-term split of a pair, lo PRE-SCALED by 2^11 (keeps lo in the normal
// fp16 range regardless of |v| -> immune to denorm flush; (v-hi) and *2048
// are exact fp32 ops). r[0] = packed hi pair, r[1] = packed lo*2048 pair.
// v = hi + lo'*2^-11 with error <= 2^-22 |v|.
static __device__ __forceinline__ uint2v split2s(float x, float y) {
    f16x2 h = __builtin_amdgcn_cvt_pkrtz(x, y);
    f16x2 l = __builtin_amdgcn_cvt_pkrtz((x - (float)h[0]) * 2048.f,
                                         (y - (float)h[1]) * 2048.f);
    uint2v r;
    r[0] = __builtin_bit_cast(unsigned int, h);
    r[1] = __builtin_bit_cast(unsigned int, l);
    return r;
}
static __device__ __forceinline__ void split8s(f32x4 A, f32x4 B,
                                               uint4v* hi, uint4v* lo) {
    uint2v r0 = split2s(A[0], A[1]);
    uint2v r1 = split2s(A[2], A[3]);
    uint2v r2 = split2s(B[0], B[1]);
    uint2v r3 = split2s(B[2], B[3]);
    uint4v h, l;
    h[0] = r0[0]; l[0] = r0[1];
    h[1] = r1[0]; l[1] = r1[1];
    h[2] = r2[0]; l[2] = r2[1];
    h[3] = r3[0]; l[3] = r3[1];
    *hi = h; *lo = l;
}

// ---------------------------------------------------------------------------
// R17 prep: precompute (once per launch, removes 998x-redundant VALU work)
//   blocks 0..15  : split fp16 weight images for (layer=bid>>3, l=bid&7),
//                   EXACT padded LDS layout (pads zeroed), + per-l vec pack
//   blocks 16..1013: E0[t] = b0 + W0[:, :16] @ emb[t]  (t = bid-16)
// Same math/order as the in-kernel fallback -> bit-identical results.
// ---------------------------------------------------------------------------
__global__ __launch_bounds__(256) void prep_ws(
    const float* __restrict__ gW0p, const float* __restrict__ gb0p,
    const float* __restrict__ gW1p, const float* __restrict__ gb1p,
    const float* __restrict__ gW2p, const float* __restrict__ gb2p,
    const float* __restrict__ gW3p, const float* __restrict__ embp,
    char* __restrict__ ws)
{
    const int tid = threadIdx.x;
    const int bid = blockIdx.x;
    __shared__ float se[16];

    if (bid < 16) {
        const int layer = bid >> 3, l = bid & 7;
        const float* src = (layer ? gW2p : gW1p) + (size_t)l * 4096;
        u16* img = (u16*)(ws + (size_t)bid * IMG_BYTES);
        const int srow = tid >> 2, scol = (tid & 3) * 16;
        const f32x4* g = (const f32x4*)src + tid * 4;
#pragma unroll
        for (int h = 0; h < 2; ++h) {
            uint4v hi, lo;
            split8s(g[h * 2], g[h * 2 + 1], &hi, &lo);
            const int o = srow * STRW + scol + h * 8;
            *(uint4v*)&img[o] = hi;
            *(uint4v*)&img[TILE_U16 + o] = lo;
        }
        if ((tid & 3) == 3) {          // zero the 16B row pads (never read)
            const uint4v z = {0, 0, 0, 0};
            *(uint4v*)&img[srow * STRW + 64] = z;
            *(uint4v*)&img[TILE_U16 + srow * STRW + 64] = z;
        }
        if (layer == 0 && tid < 64) {  // pack per-l small vectors
            float* vec = (float*)(ws + WS_VEC_OFF) + l * 256;
            const float* r = gW0p + (size_t)(l * 64 + tid) * 17;
            vec[tid]       = r[16];            // w0c
            vec[64 + tid]  = gb1p[l * 64 + tid];
            vec[128 + tid] = gb2p[l * 64 + tid];
            vec[192 + tid] = gW3p[l * 64 + tid];
        }
    } else {
        const int t = bid - 16;
        if (tid < 16) se[tid] = embp[(t + 2) * 16 + tid];
        __syncthreads();
        float* eo = (float*)(ws + WS_E0_OFF) + (size_t)t * 512;
#pragma unroll
        for (int p = 0; p < 2; ++p) {
            const int idx = tid + p * 256;       // [l][row]
            const int l = idx >> 6, row = idx & 63;
            const float* r = gW0p + (size_t)(l * 64 + row) * 17;
            float acc = gb0p[l * 64 + row];
#pragma unroll
            for (int e = 0; e < 16; ++e) acc = fmaf(r[e], se[e], acc);
            eo[idx] = acc;
        }
    }
}

// ---------------------------------------------------------------------------
// R17: fp16 2-term split MFMA (R16 math, bit-identical) with weight tiles,
// E0, and per-l vectors precomputed in workspace by prep_ws. Staging becomes
// 4-5 global_load_lds dwordx4 (async, no VALU) per tile; wave-0 serial E0
// compute removed from the B1->B2 critical path. Fallback (!use_ws) keeps
// the R16-verified in-kernel staging. LDS layout/indexing unchanged.
// ---------------------------------------------------------------------------
__global__ __launch_bounds__(256, 4) void mlp_h2(
    const float* __restrict__ xp,  const float* __restrict__ embp,
    const float* __restrict__ gW0p, const float* __restrict__ gb0p,
    const float* __restrict__ gW1p, const float* __restrict__ gb1p,
    const float* __restrict__ gW2p, const float* __restrict__ gb2p,
    const float* __restrict__ gW3p, const float* __restrict__ gb3p,
    float* __restrict__ out, const char* __restrict__ wsr, int use_ws)
{
    __shared__ u16 sW2[2][TILE_U16];           // [0]=hi(sWa) [1]=lo(sWb), contiguous
    __shared__ unsigned int scrH[4][16 * STRU];
    __shared__ unsigned int scrD[4][16 * STRU];
    __shared__ float sVec[256];                // [w0c|b1|b2|w3] x 64
    __shared__ float sE0[64], semb[16];

    u16* const sWa = sW2[0];
    u16* const sWb = sW2[1];
    float* const sw0c = sVec;
    float* const sb1  = sVec + 64;
    float* const sb2  = sVec + 128;
    float* const sw3  = sVec + 192;

    const int tid = threadIdx.x;
    const int wave = tid >> 6, lane = tid & 63;
    const int q = lane >> 4, s = lane & 15;
    const int t = blockIdx.x;
    const int bsmp = wave * 16 + s;
    const f32x4 zf = {0.f, 0.f, 0.f, 0.f};

    if (!use_ws && tid < 16) semb[tid] = embp[(t + 2) * 16 + tid];
    float ldAcc = 0.f;

    const int srow = tid >> 2, scol = (tid & 3) * 16;

    for (int l = 0; l < 8; ++l) {
        __syncthreads();   // B1: prior-iter tile reads done; semb visible (l=0)
        if (use_ws) {
            // ---- async stage W1(l) image (preformatted hi/lo, incl. pads) ----
            const char* img = wsr + (size_t)l * IMG_BYTES;
#pragma unroll
            for (int c = 0; c < 4; ++c)
                gll16(img + c * 4096 + tid * 16, (char*)sW2 + c * 4096 + wave * 1024);
            if (tid < 128)   // tail 2048B: waves 0-1 only
                gll16(img + 16384 + tid * 16, (char*)sW2 + 16384 + wave * 1024);
            sVec[tid] = *(const float*)(wsr + WS_VEC_OFF + (size_t)(l * 256 + tid) * 4);
            if (tid < 64)
                sE0[tid] = *(const float*)(wsr + WS_E0_OFF +
                                           ((size_t)t * 512 + l * 64 + tid) * 4);
            asm volatile("s_waitcnt vmcnt(0)" ::: "memory");
        } else {
            {   // ---- stage W1(l) as hi / scaled-lo fp16 tiles ----
                const f32x4* g = (const f32x4*)(gW1p + (size_t)l * 4096) + tid * 4;
#pragma unroll
                for (int h = 0; h < 2; ++h) {
                    uint4v hi, lo;
                    split8s(g[h * 2], g[h * 2 + 1], &hi, &lo);
                    const int o = srow * STRW + scol + h * 8;
                    *(uint4v*)&sWa[o] = hi;
                    *(uint4v*)&sWb[o] = lo;
                }
            }
            if (tid < 64) {   // E0 = b0 + W0[:, :16] @ emb; w0c; small vectors
                const float* r = gW0p + (size_t)(l * 64 + tid) * 17;
                float acc = gb0p[l * 64 + tid];
#pragma unroll
                for (int e = 0; e < 16; e++) acc = fmaf(r[e], semb[e], acc);
                sE0[tid]  = acc;
                sw0c[tid] = r[16];
                sb1[tid]  = gb1p[l * 64 + tid];
                sb2[tid]  = gb2p[l * 64 + tid];
                sw3[tid]  = gW3p[l * 64 + tid];
            }
        }
        __syncthreads();   // B2

        const float b3v = gb3p[l];
        const float xv = xp[(size_t)(bsmp * 1000 + t + 2) * 8 + l];

        // ---- layer 0 -> hi/scaled-lo fp16 B-frags (R12-verified indexing) ----
        half8 H0a[2], H0b[2], D0a[2], D0b[2];
#pragma unroll
        for (int kc = 0; kc < 2; ++kc) {
            f32x4 eA = *(const f32x4*)&sE0[kc * 32 + q * 8];
            f32x4 eB = *(const f32x4*)&sE0[kc * 32 + q * 8 + 4];
            f32x4 wA = *(const f32x4*)&sw0c[kc * 32 + q * 8];
            f32x4 wB = *(const f32x4*)&sw0c[kc * 32 + q * 8 + 4];
            float hv[8], dv[8];
#pragma unroll
            for (int i = 0; i < 8; ++i) {
                float w  = (i < 4) ? wA[i] : wB[i - 4];
                float e0 = (i < 4) ? eA[i] : eB[i - 4];
                float p  = fmaf(w, xv, e0);
                hv[i] = fmaxf(p, 0.2f * p);
                dv[i] = (p >= 0.f ? 1.f : 0.2f) * w;
            }
            uint4v Ha, Hb, Da, Db;
#pragma unroll
            for (int d2 = 0; d2 < 4; ++d2) {
                uint2v rh = split2s(hv[2 * d2], hv[2 * d2 + 1]);
                uint2v rd = split2s(dv[2 * d2], dv[2 * d2 + 1]);
                Ha[d2] = rh[0]; Hb[d2] = rh[1];
                Da[d2] = rd[0]; Db[d2] = rd[1];
            }
            H0a[kc] = __builtin_bit_cast(half8, Ha);
            H0b[kc] = __builtin_bit_cast(half8, Hb);
            D0a[kc] = __builtin_bit_cast(half8, Da);
            D0b[kc] = __builtin_bit_cast(half8, Db);
        }

        // ---- layer 1: 3-MFMA split GEMM, dual accumulators ----
        f32x4 aA[4], aX[4], tA[4], tX[4];
#pragma unroll
        for (int mb = 0; mb < 4; ++mb) { aA[mb] = zf; aX[mb] = zf; tA[mb] = zf; tX[mb] = zf; }
#pragma unroll
        for (int kc = 0; kc < 2; ++kc) {
#pragma unroll
            for (int mb = 0; mb < 4; ++mb) {
                const int wo = (mb * 16 + s) * STRW + kc * 32 + q * 8;
                half8 wa = __builtin_bit_cast(half8, *(const uint4v*)&sWa[wo]);
                half8 wb = __builtin_bit_cast(half8, *(const uint4v*)&sWb[wo]);
                aA[mb] = __builtin_amdgcn_mfma_f32_16x16x32_f16(wa, H0a[kc], aA[mb], 0, 0, 0);
                aX[mb] = __builtin_amdgcn_mfma_f32_16x16x32_f16(wa, H0b[kc], aX[mb], 0, 0, 0);
                aX[mb] = __builtin_amdgcn_mfma_f32_16x16x32_f16(wb, H0a[kc], aX[mb], 0, 0, 0);
                tA[mb] = __builtin_amdgcn_mfma_f32_16x16x32_f16(wa, D0a[kc], tA[mb], 0, 0, 0);
                tX[mb] = __builtin_amdgcn_mfma_f32_16x16x32_f16(wa, D0b[kc], tX[mb], 0, 0, 0);
                tX[mb] = __builtin_amdgcn_mfma_f32_16x16x32_f16(wb, D0a[kc], tX[mb], 0, 0, 0);
            }
        }

        // ---- activation + 2-pass hi/lo C->B transform (per-wave scratch) ----
        uint2v hpH[4], hpL[4], dpH[4], dpL[4];
#pragma unroll
        for (int mb = 0; mb < 4; ++mb) {
            f32x4 b1v = *(const f32x4*)&sb1[mb * 16 + q * 4];
            float hv[4], dv[4];
#pragma unroll
            for (int i = 0; i < 4; ++i) {
                float p  = fmaf(aX[mb][i], INVS, aA[mb][i]) + b1v[i];
                float dt = fmaf(tX[mb][i], INVS, tA[mb][i]);
                hv[i] = fmaxf(p, 0.2f * p);
                dv[i] = (p >= 0.f ? 1.f : 0.2f) * dt;
            }
            uint2v r0 = split2s(hv[0], hv[1]);
            uint2v r1 = split2s(hv[2], hv[3]);
            uint2v r2 = split2s(dv[0], dv[1]);
            uint2v r3 = split2s(dv[2], dv[3]);
            hpH[mb][0] = r0[0]; hpL[mb][0] = r0[1];
            hpH[mb][1] = r1[0]; hpL[mb][1] = r1[1];
            dpH[mb][0] = r2[0]; dpL[mb][0] = r2[1];
            dpH[mb][1] = r3[0]; dpL[mb][1] = r3[1];
        }
        unsigned int* mH = scrH[wave];
        unsigned int* mD = scrD[wave];
        half8 H1a[2], H1b[2], D1a[2], D1b[2];
        // pass 1 (hi)
#pragma unroll
        for (int mb = 0; mb < 4; ++mb) {
            *(uint2v*)&mH[s * STRU + mb * 8 + q * 2] = hpH[mb];
            *(uint2v*)&mD[s * STRU + mb * 8 + q * 2] = dpH[mb];
        }
        LDSFENCE();
#pragma unroll
        for (int kc = 0; kc < 2; ++kc) {
            H1a[kc] = __builtin_bit_cast(half8, *(const uint4v*)&mH[s * STRU + kc * 16 + q * 4]);
            D1a[kc] = __builtin_bit_cast(half8, *(const uint4v*)&mD[s * STRU + kc * 16 + q * 4]);
        }
        LDSFENCE();
        // pass 2 (scaled lo)
#pragma unroll
        for (int mb = 0; mb < 4; ++mb) {
            *(uint2v*)&mH[s * STRU + mb * 8 + q * 2] = hpL[mb];
            *(uint2v*)&mD[s * STRU + mb * 8 + q * 2] = dpL[mb];
        }
        LDSFENCE();
#pragma unroll
        for (int kc = 0; kc < 2; ++kc) {
            H1b[kc] = __builtin_bit_cast(half8, *(const uint4v*)&mH[s * STRU + kc * 16 + q * 4]);
            D1b[kc] = __builtin_bit_cast(half8, *(const uint4v*)&mD[s * STRU + kc * 16 + q * 4]);
        }

        __syncthreads();   // B3: all waves done reading W1 tiles
        if (use_ws) {
            // ---- async stage W2(l) image into the same tiles ----
            const char* img = wsr + (size_t)(8 + l) * IMG_BYTES;
#pragma unroll
            for (int c = 0; c < 4; ++c)
                gll16(img + c * 4096 + tid * 16, (char*)sW2 + c * 4096 + wave * 1024);
            if (tid < 128)
                gll16(img + 16384 + tid * 16, (char*)sW2 + 16384 + wave * 1024);
            asm volatile("s_waitcnt vmcnt(0)" ::: "memory");
        } else {
            const f32x4* g = (const f32x4*)(gW2p + (size_t)l * 4096) + tid * 4;
#pragma unroll
            for (int h = 0; h < 2; ++h) {
                uint4v hi, lo;
                split8s(g[h * 2], g[h * 2 + 1], &hi, &lo);
                const int o = srow * STRW + scol + h * 8;
                *(uint4v*)&sWa[o] = hi;
                *(uint4v*)&sWb[o] = lo;
            }
        }
        __syncthreads();   // B4

        // ---- layer 2: 3-MFMA split GEMM, dual accumulators ----
#pragma unroll
        for (int mb = 0; mb < 4; ++mb) { aA[mb] = zf; aX[mb] = zf; tA[mb] = zf; tX[mb] = zf; }
#pragma unroll
        for (int kc = 0; kc < 2; ++kc) {
#pragma unroll
            for (int mb = 0; mb < 4; ++mb) {
                const int wo = (mb * 16 + s) * STRW + kc * 32 + q * 8;
                half8 wa = __builtin_bit_cast(half8, *(const uint4v*)&sWa[wo]);
                half8 wb = __builtin_bit_cast(half8, *(const uint4v*)&sWb[wo]);
                aA[mb] = __builtin_amdgcn_mfma_f32_16x16x32_f16(wa, H1a[kc], aA[mb], 0, 0, 0);
                aX[mb] = __builtin_amdgcn_mfma_f32_16x16x32_f16(wa, H1b[kc], aX[mb], 0, 0, 0);
                aX[mb] = __builtin_amdgcn_mfma_f32_16x16x32_f16(wb, H1a[kc], aX[mb], 0, 0, 0);
                tA[mb] = __builtin_amdgcn_mfma_f32_16x16x32_f16(wa, D1a[kc], tA[mb], 0, 0, 0);
                tX[mb] = __builtin_amdgcn_mfma_f32_16x16x32_f16(wa, D1b[kc], tX[mb], 0, 0, 0);
                tX[mb] = __builtin_amdgcn_mfma_f32_16x16x32_f16(wb, D1a[kc], tX[mb], 0, 0, 0);
            }
        }

        // ---- layer 3 + butterfly + outputs ----
        float rs = 0.f, js = 0.f;
#pragma unroll
        for (int mb = 0; mb < 4; ++mb) {
            f32x4 b2v = *(const f32x4*)&sb2[mb * 16 + q * 4];
            f32x4 w3v = *(const f32x4*)&sw3[mb * 16 + q * 4];
#pragma unroll
            for (int i = 0; i < 4; ++i) {
                float p  = fmaf(aX[mb][i], INVS, aA[mb][i]) + b2v[i];
                float dt = fmaf(tX[mb][i], INVS, tA[mb][i]);
                float h = fmaxf(p, 0.2f * p);
                float d = (p >= 0.f ? 1.f : 0.2f) * dt;
                rs = fmaf(w3v[i], h, rs);
                js = fmaf(w3v[i], d, js);
            }
        }
        rs += __shfl_xor(rs, 16, 64); rs += __shfl_xor(rs, 32, 64);
        js += __shfl_xor(js, 16, 64); js += __shfl_xor(js, 32, 64);
        if (lane < 16)
            out[(size_t)(bsmp * LENT + t) * 8 + l] = rs + b3v;
        ldAcc += __logf(fabsf(js));
    }

    if (lane < 16)
        out[(size_t)NSAMP * 8 + (size_t)bsmp * LENT + t] = ldAcc;
}

extern "C" void kernel_launch(void* const* d_in, const int* in_sizes, int n_in,
                              void* d_out, int out_size, void* d_ws, size_t ws_size,
                              hipStream_t stream) {
    (void)in_sizes; (void)n_in; (void)out_size;
    const int use_ws = (d_ws != nullptr && ws_size >= WS_NEED) ? 1 : 0;
    if (use_ws) {
        prep_ws<<<dim3(16 + LENT), 256, 0, stream>>>(
            (const float*)d_in[2], (const float*)d_in[3],
            (const float*)d_in[4], (const float*)d_in[5],
            (const float*)d_in[6], (const float*)d_in[7],
            (const float*)d_in[8], (const float*)d_in[1],
            (char*)d_ws);
    }
    mlp_h2<<<dim3(LENT), 256, 0, stream>>>(
        (const float*)d_in[0], (const float*)d_in[1],
        (const float*)d_in[2], (const float*)d_in[3],
        (const float*)d_in[4], (const float*)d_in[5],
        (const float*)d_in[6], (const float*)d_in[7],
        (const float*)d_in[8], (const float*)d_in[9],
        (float*)d_out, (const char*)d_ws, use_ws);
}